// Round 6
// baseline (800.393 us; speedup 1.0000x reference)
//
#include <hip/hip_runtime.h>
#include <hip/hip_bf16.h>
#include <cstddef>

#define NODES  100000
#define EDGES  3200000
#define ETOT   3300000   // EDGES + NODES self-loops
#define NGRAPH 64
#define HDIM   256
#define BSHIFT 9
#define NBUCK  196       // ceil(NODES / 512)
#define BCAP   19456     // records/bucket: mean 16896 + 20 sigma

typedef __hip_bfloat16 bf16;
typedef short bf16x8 __attribute__((ext_vector_type(8)));
typedef float f32x4 __attribute__((ext_vector_type(4)));
typedef int   i32x2 __attribute__((ext_vector_type(2)));
typedef unsigned u32x2 __attribute__((ext_vector_type(2)));
typedef unsigned u32x4 __attribute__((ext_vector_type(4)));

__device__ __forceinline__ float blo(unsigned u) { return __uint_as_float(u << 16); }
__device__ __forceinline__ float bhi(unsigned u) { return __uint_as_float(u & 0xffff0000u); }

// ---------------------------------------------------------------- fp32 -> bf16 copy of x
__global__ void xcast_kernel(const float* __restrict__ x, bf16* __restrict__ xb) {
    int i = blockIdx.x * 256 + threadIdx.x;            // 4 elements each
    if ((size_t)i * 4 >= (size_t)NODES * 128) return;
    float4 v = *(const float4*)(x + (size_t)i * 4);
    union { __hip_bfloat162 h[2]; uint2 u; } pk;
    pk.h[0] = __float22bfloat162_rn(make_float2(v.x, v.y));
    pk.h[1] = __float22bfloat162_rn(make_float2(v.z, v.w));
    *(uint2*)(xb + (size_t)i * 4) = pk.u;
}

// ---------------------------------------------------------------- W1[128,256]->W1t, W2[256,256]->W2t (bf16, transposed)
__global__ void wcast_kernel(const float* __restrict__ W1, const float* __restrict__ W2,
                             bf16* __restrict__ W1t, bf16* __restrict__ W2t) {
    int i = blockIdx.x * 256 + threadIdx.x;
    if (i < 128 * 256) {
        int n = i / 128, k = i - n * 128;
        W1t[i] = __float2bfloat16(W1[(size_t)k * 256 + n]);
    } else if (i < 128 * 256 + 256 * 256) {
        int q = i - 128 * 256;
        int n = q / 256, k = q - n * 256;
        W2t[q] = __float2bfloat16(W2[(size_t)k * 256 + n]);
    }
}

// ---------------------------------------------------------------- fill phase 1: bucket records
__global__ __launch_bounds__(1024) void fillp1_kernel(const int* __restrict__ row,
                                                      const int* __restrict__ col,
                                                      int* __restrict__ gcnt,
                                                      uint2* __restrict__ recs) {
    __shared__ int hist[NBUCK];
    __shared__ int base[NBUCK];
    int t = threadIdx.x;
    if (t < NBUCK) hist[t] = 0;
    __syncthreads();
    int e0 = blockIdx.x * 16384;
    int r[16], c[16], rk[16];
    #pragma unroll
    for (int i = 0; i < 16; i++) {
        int e = e0 + i * 1024 + t;
        r[i] = -1;
        if (e < ETOT) {
            if (e < EDGES) { r[i] = row[e]; c[i] = col[e]; }
            else           { r[i] = e - EDGES; c[i] = r[i]; }
            rk[i] = atomicAdd(&hist[c[i] >> BSHIFT], 1);
        }
    }
    __syncthreads();
    if (t < NBUCK && hist[t] > 0) base[t] = atomicAdd(&gcnt[t], hist[t]);
    __syncthreads();
    #pragma unroll
    for (int i = 0; i < 16; i++) {
        if (r[i] >= 0) {
            int b = c[i] >> BSHIFT;
            recs[(size_t)b * BCAP + base[b] + rk[i]] = make_uint2((unsigned)r[i], (unsigned)c[i]);
        }
    }
}

// ---------------------------------------------------------------- bucket base scan (tiny)
__global__ void bscan_kernel(const int* __restrict__ gcnt, int* __restrict__ bbase) {
    __shared__ int part[256];
    int t = threadIdx.x;
    int v0 = (t < NBUCK) ? gcnt[t] : 0;
    part[t] = v0;
    __syncthreads();
    for (int off = 1; off < 256; off <<= 1) {
        int v = (t >= off) ? part[t - off] : 0;
        __syncthreads();
        part[t] += v;
        __syncthreads();
    }
    if (t < NBUCK) bbase[t] = part[t] - v0;   // exclusive
}

// ---------------------------------------------------------------- per-bucket counting sort
__global__ __launch_bounds__(256) void build_kernel(const uint2* __restrict__ recs,
                                                    const int* __restrict__ gcnt,
                                                    const int* __restrict__ bbase,
                                                    int* __restrict__ rowptr,
                                                    float* __restrict__ dinv,
                                                    int* __restrict__ csr) {
    __shared__ int hist[512];
    __shared__ int cur[512];
    __shared__ int part[256];
    const int b = blockIdx.x, t = threadIdx.x;
    const int n0 = b << BSHIFT;
    const int cnt = gcnt[b];
    const int base = bbase[b];
    hist[t] = 0; hist[t + 256] = 0;
    __syncthreads();
    const uint2* rb = recs + (size_t)b * BCAP;
    for (int i = t; i < cnt; i += 256) atomicAdd(&hist[(int)rb[i].y - n0], 1);
    __syncthreads();
    int h0 = hist[2 * t], h1 = hist[2 * t + 1];
    part[t] = h0 + h1;
    __syncthreads();
    for (int off = 1; off < 256; off <<= 1) {
        int v = (t >= off) ? part[t - off] : 0;
        __syncthreads();
        part[t] += v;
        __syncthreads();
    }
    int ex = (t == 0) ? 0 : part[t - 1];       // exclusive over node pairs
    cur[2 * t]     = ex;
    cur[2 * t + 1] = ex + h0;
    int v0 = n0 + 2 * t, v1 = v0 + 1;
    if (v0 < NODES) { rowptr[v0] = base + ex;      dinv[v0] = rsqrtf((float)h0); }
    if (v1 < NODES) { rowptr[v1] = base + ex + h0; dinv[v1] = rsqrtf((float)h1); }
    if (b == 0 && t == 0) rowptr[NODES] = ETOT;
    __syncthreads();
    for (int i = t; i < cnt; i += 256) {
        uint2 r = rb[i];
        int pos = atomicAdd(&cur[(int)r.y - n0], 1);
        csr[base + pos] = (int)r.x;
    }
}

// ---------------------------------------------------------------- csr -> (src, dinv[src]) pairs
__global__ void remap_kernel(const int* __restrict__ csr, const float* __restrict__ dinv,
                             int* __restrict__ csrp) {
    int e = blockIdx.x * 256 + threadIdx.x;
    if (e >= ETOT) return;
    int s = csr[e];
    i32x2 pr = { s, __float_as_int(dinv[s]) };
    __builtin_nontemporal_store(pr, (i32x2*)(csrp + 2 * (size_t)e));
}

// ---------------------------------------------------------------- pull aggregation, H=128
// 2 nodes/wave, half-wave per node, u32x2 (4 dims) per lane, unroll 4.
__global__ void agg1_kernel(const bf16* __restrict__ xb, const int* __restrict__ rowptr,
                            const int* __restrict__ csrp, const float* __restrict__ dinv,
                            bf16* __restrict__ out) {
    int w    = (blockIdx.x * blockDim.x + threadIdx.x) >> 6;
    int lane = threadIdx.x & 63;
    int half = lane >> 5, li = lane & 31;
    int node = w * 2 + half;
    if (node >= NODES) return;
    int beg = rowptr[node], end = rowptr[node + 1];
    float a0 = 0.f, a1 = 0.f, a2 = 0.f, a3 = 0.f;
    int j = beg;
    for (; j + 3 < end; j += 4) {
        i32x2 e0 = __builtin_nontemporal_load((const i32x2*)(csrp + 2 * (size_t)(j + 0)));
        i32x2 e1 = __builtin_nontemporal_load((const i32x2*)(csrp + 2 * (size_t)(j + 1)));
        i32x2 e2 = __builtin_nontemporal_load((const i32x2*)(csrp + 2 * (size_t)(j + 2)));
        i32x2 e3 = __builtin_nontemporal_load((const i32x2*)(csrp + 2 * (size_t)(j + 3)));
        u32x2 q0 = *(const u32x2*)(xb + (size_t)e0.x * 128 + li * 4);
        u32x2 q1 = *(const u32x2*)(xb + (size_t)e1.x * 128 + li * 4);
        u32x2 q2 = *(const u32x2*)(xb + (size_t)e2.x * 128 + li * 4);
        u32x2 q3 = *(const u32x2*)(xb + (size_t)e3.x * 128 + li * 4);
        float w0 = __int_as_float(e0.y), w1 = __int_as_float(e1.y);
        float w2 = __int_as_float(e2.y), w3 = __int_as_float(e3.y);
        a0 += w0 * blo(q0.x) + w1 * blo(q1.x) + w2 * blo(q2.x) + w3 * blo(q3.x);
        a1 += w0 * bhi(q0.x) + w1 * bhi(q1.x) + w2 * bhi(q2.x) + w3 * bhi(q3.x);
        a2 += w0 * blo(q0.y) + w1 * blo(q1.y) + w2 * blo(q2.y) + w3 * blo(q3.y);
        a3 += w0 * bhi(q0.y) + w1 * bhi(q1.y) + w2 * bhi(q2.y) + w3 * bhi(q3.y);
    }
    for (; j < end; j++) {
        i32x2 e0 = __builtin_nontemporal_load((const i32x2*)(csrp + 2 * (size_t)j));
        float w0 = __int_as_float(e0.y);
        u32x2 q0 = *(const u32x2*)(xb + (size_t)e0.x * 128 + li * 4);
        a0 += w0 * blo(q0.x);
        a1 += w0 * bhi(q0.x);
        a2 += w0 * blo(q0.y);
        a3 += w0 * bhi(q0.y);
    }
    float d = dinv[node];
    union { __hip_bfloat162 h[2]; u32x2 u; } pk;
    pk.h[0] = __float22bfloat162_rn(make_float2(a0 * d, a1 * d));
    pk.h[1] = __float22bfloat162_rn(make_float2(a2 * d, a3 * d));
    __builtin_nontemporal_store(pk.u, (u32x2*)(out + (size_t)node * 128 + li * 4));
}

// ---------------------------------------------------------------- pull aggregation, H=256
// 2 nodes/wave, half-wave per node, u32x4 (8 dims) per lane, unroll 4.
__global__ void agg2_kernel(const bf16* __restrict__ hb, const int* __restrict__ rowptr,
                            const int* __restrict__ csrp, const float* __restrict__ dinv,
                            bf16* __restrict__ out) {
    int w    = (blockIdx.x * blockDim.x + threadIdx.x) >> 6;
    int lane = threadIdx.x & 63;
    int half = lane >> 5, li = lane & 31;
    int node = w * 2 + half;
    if (node >= NODES) return;
    int beg = rowptr[node], end = rowptr[node + 1];
    float a[8] = {};
    int j = beg;
    for (; j + 3 < end; j += 4) {
        i32x2 e0 = __builtin_nontemporal_load((const i32x2*)(csrp + 2 * (size_t)(j + 0)));
        i32x2 e1 = __builtin_nontemporal_load((const i32x2*)(csrp + 2 * (size_t)(j + 1)));
        i32x2 e2 = __builtin_nontemporal_load((const i32x2*)(csrp + 2 * (size_t)(j + 2)));
        i32x2 e3 = __builtin_nontemporal_load((const i32x2*)(csrp + 2 * (size_t)(j + 3)));
        u32x4 q0 = *(const u32x4*)(hb + (size_t)e0.x * 256 + li * 8);
        u32x4 q1 = *(const u32x4*)(hb + (size_t)e1.x * 256 + li * 8);
        u32x4 q2 = *(const u32x4*)(hb + (size_t)e2.x * 256 + li * 8);
        u32x4 q3 = *(const u32x4*)(hb + (size_t)e3.x * 256 + li * 8);
        float w0 = __int_as_float(e0.y), w1 = __int_as_float(e1.y);
        float w2 = __int_as_float(e2.y), w3 = __int_as_float(e3.y);
        a[0] += w0 * blo(q0.x) + w1 * blo(q1.x) + w2 * blo(q2.x) + w3 * blo(q3.x);
        a[1] += w0 * bhi(q0.x) + w1 * bhi(q1.x) + w2 * bhi(q2.x) + w3 * bhi(q3.x);
        a[2] += w0 * blo(q0.y) + w1 * blo(q1.y) + w2 * blo(q2.y) + w3 * blo(q3.y);
        a[3] += w0 * bhi(q0.y) + w1 * bhi(q1.y) + w2 * bhi(q2.y) + w3 * bhi(q3.y);
        a[4] += w0 * blo(q0.z) + w1 * blo(q1.z) + w2 * blo(q2.z) + w3 * blo(q3.z);
        a[5] += w0 * bhi(q0.z) + w1 * bhi(q1.z) + w2 * bhi(q2.z) + w3 * bhi(q3.z);
        a[6] += w0 * blo(q0.w) + w1 * blo(q1.w) + w2 * blo(q2.w) + w3 * blo(q3.w);
        a[7] += w0 * bhi(q0.w) + w1 * bhi(q1.w) + w2 * bhi(q2.w) + w3 * bhi(q3.w);
    }
    for (; j < end; j++) {
        i32x2 e0 = __builtin_nontemporal_load((const i32x2*)(csrp + 2 * (size_t)j));
        float w0 = __int_as_float(e0.y);
        u32x4 q0 = *(const u32x4*)(hb + (size_t)e0.x * 256 + li * 8);
        a[0] += w0 * blo(q0.x); a[1] += w0 * bhi(q0.x);
        a[2] += w0 * blo(q0.y); a[3] += w0 * bhi(q0.y);
        a[4] += w0 * blo(q0.z); a[5] += w0 * bhi(q0.z);
        a[6] += w0 * blo(q0.w); a[7] += w0 * bhi(q0.w);
    }
    float d = dinv[node];
    union { __hip_bfloat162 h[4]; u32x4 u; } pk;
    pk.h[0] = __float22bfloat162_rn(make_float2(a[0] * d, a[1] * d));
    pk.h[1] = __float22bfloat162_rn(make_float2(a[2] * d, a[3] * d));
    pk.h[2] = __float22bfloat162_rn(make_float2(a[4] * d, a[5] * d));
    pk.h[3] = __float22bfloat162_rn(make_float2(a[6] * d, a[7] * d));
    __builtin_nontemporal_store(pk.u, (u32x4*)(out + (size_t)node * 256 + li * 8));
}

// ---------------------------------------------------------------- bf16 MFMA GEMM 128x128
template <int K>
__global__ __launch_bounds__(256) void mgemm_kernel(const bf16* __restrict__ A,
                                                    const bf16* __restrict__ Bt,
                                                    const float* __restrict__ bias,
                                                    bf16* __restrict__ Cb) {
    __shared__ short As[128][40];   // [m][k], +8 pad
    __shared__ short Bs[128][40];   // [n][k]
    const int t    = threadIdx.x;
    const int bm   = (int)(blockIdx.x >> 1) * 128;
    const int bn   = (int)(blockIdx.x & 1) * 128;
    const int lane = t & 63;
    const int wave = t >> 6;
    const int wm   = (wave >> 1) * 64, wn = (wave & 1) * 64;
    const int m16  = lane & 15, kq = lane >> 4;
    f32x4 acc[4][4] = {};

    for (int k0 = 0; k0 < K; k0 += 32) {
        #pragma unroll
        for (int h = 0; h < 2; h++) {
            int q = t * 2 + h;
            int rr = q >> 2, seg = q & 3;
            uint4 va = {0u, 0u, 0u, 0u};
            int grow = bm + rr;
            if (grow < NODES) va = *(const uint4*)(A + (size_t)grow * K + k0 + seg * 8);
            *(uint4*)&As[rr][seg * 8] = va;
            uint4 vb = *(const uint4*)(Bt + (size_t)(bn + rr) * K + k0 + seg * 8);
            *(uint4*)&Bs[rr][seg * 8] = vb;
        }
        __syncthreads();
        bf16x8 af[4], bf_[4];
        #pragma unroll
        for (int i = 0; i < 4; i++) {
            af[i]  = *(const bf16x8*)&As[wm + i * 16 + m16][kq * 8];
            bf_[i] = *(const bf16x8*)&Bs[wn + i * 16 + m16][kq * 8];
        }
        #pragma unroll
        for (int mt = 0; mt < 4; mt++)
            #pragma unroll
            for (int nt = 0; nt < 4; nt++)
                acc[mt][nt] = __builtin_amdgcn_mfma_f32_16x16x32_bf16(af[mt], bf_[nt],
                                                                     acc[mt][nt], 0, 0, 0);
        __syncthreads();
    }

    // C/D layout: col = lane&15, row = (lane>>4)*4 + reg
    #pragma unroll
    for (int mt = 0; mt < 4; mt++) {
        #pragma unroll
        for (int r = 0; r < 4; r++) {
            int row = bm + wm + mt * 16 + kq * 4 + r;
            if (row >= NODES) continue;
            #pragma unroll
            for (int nt = 0; nt < 4; nt++) {
                int colb = bn + wn + nt * 16 + m16;
                float v = fmaxf(acc[mt][nt][r] + bias[colb], 0.f);
                Cb[(size_t)row * 256 + colb] = __float2bfloat16(v);
            }
        }
    }
}

// ---------------------------------------------------------------- segmented mean-pool sum
__global__ void pool_kernel(const bf16* __restrict__ h2, const int* __restrict__ batch,
                            float* __restrict__ sums) {
    int lane = threadIdx.x & 63;
    int sub  = threadIdx.x >> 6;                   // 0..3
    int col  = blockIdx.y * 64 + lane;
    int r0   = blockIdx.x * 1024 + sub * 256;
    if (r0 >= NODES) return;
    int r1 = r0 + 256; if (r1 > NODES) r1 = NODES;
    float acc = 0.f;
    int g = batch[r0];
    for (int r = r0; r < r1; r++) {
        int gg = batch[r];
        if (gg != g) { atomicAdd(&sums[g * 256 + col], acc); acc = 0.f; g = gg; }
        acc += __bfloat162float(h2[(size_t)r * 256 + col]);
    }
    atomicAdd(&sums[g * 256 + col], acc);
}

// ---------------------------------------------------------------- pooled @ Wl + bl
__global__ void final_kernel(const float* __restrict__ sums, const int* __restrict__ batch,
                             const float* __restrict__ Wl, const float* __restrict__ bl,
                             float* __restrict__ out) {
    int g = blockIdx.x;
    int l = threadIdx.x;
    int lo = 0, hi = NODES;
    while (lo < hi) { int m = (lo + hi) >> 1; if (batch[m] < g) lo = m + 1; else hi = m; }
    int lb = lo;
    lo = lb; hi = NODES;
    while (lo < hi) { int m = (lo + hi) >> 1; if (batch[m] <= g) lo = m + 1; else hi = m; }
    int cnt = lo - lb;
    float inv = 1.f / fmaxf((float)cnt, 1.f);
    float a0 = 0.f, a1 = 0.f;
    for (int k = l; k < 256; k += 64) {
        float p = sums[g * 256 + k] * inv;
        a0 += p * Wl[k * 2 + 0];
        a1 += p * Wl[k * 2 + 1];
    }
    for (int off = 32; off > 0; off >>= 1) {
        a0 += __shfl_down(a0, off, 64);
        a1 += __shfl_down(a1, off, 64);
    }
    if (l == 0) {
        out[g * 2 + 0] = a0 + bl[0];
        out[g * 2 + 1] = a1 + bl[1];
    }
}

// ---------------------------------------------------------------- launch
extern "C" void kernel_launch(void* const* d_in, const int* in_sizes, int n_in,
                              void* d_out, int out_size, void* d_ws, size_t ws_size,
                              hipStream_t stream) {
    const float* x    = (const float*)d_in[0];
    const int*   ei   = (const int*)d_in[1];
    const int*   bat  = (const int*)d_in[2];
    const float* W1   = (const float*)d_in[3];
    const float* b1   = (const float*)d_in[4];
    const float* W2   = (const float*)d_in[5];
    const float* b2   = (const float*)d_in[6];
    const float* Wl   = (const float*)d_in[7];
    const float* bl   = (const float*)d_in[8];
    float*       out  = (float*)d_out;
    const int* erow = ei;           // edge_index[0] = source
    const int* ecol = ei + EDGES;   // edge_index[1] = target

    char* p = (char*)d_ws;
    auto take = [&](size_t bytes) {
        char* r = p;
        p += (bytes + 255) & ~(size_t)255;
        return r;
    };
    float* dinv   = (float*)take((size_t)NODES * 4);
    int*   rowptr = (int*)  take((size_t)(NODES + 1) * 4);
    int*   gcnt   = (int*)  take((size_t)NBUCK * 4);
    int*   bbase  = (int*)  take((size_t)NBUCK * 4);
    int*   csr    = (int*)  take((size_t)ETOT * 4);
    float* sums   = (float*)take((size_t)NGRAPH * HDIM * 4);
    bf16*  W1t    = (bf16*) take((size_t)128 * 256 * 2);
    bf16*  W2t    = (bf16*) take((size_t)256 * 256 * 2);
    char*  reg1   = (char*) take((size_t)NODES * HDIM * 2);          // xb -> h1b
    char*  reg2   = (char*) take((size_t)NODES * HDIM * 2);          // aggbuf1 -> aggbuf2
    char*  reg3   = (char*) take((size_t)NODES * HDIM * 2);          // recs -> csrp -> h2b
    bf16*  xb      = (bf16*)reg1;    // dead after agg1
    bf16*  h1b     = (bf16*)reg1;    // born mgemm1, dead after agg2
    bf16*  aggbuf1 = (bf16*)reg2;    // born agg1, dead after mgemm1
    bf16*  aggbuf2 = (bf16*)reg2;    // born agg2, dead after mgemm2
    uint2* recs    = (uint2*)reg3;   // 30.5 MB, dead after build
    int*   csrp    = (int*)reg3;     // 26.4 MB, born remap, dead after agg2 -- wait, overlaps recs
    bf16*  h2b     = (bf16*)reg3;    // born mgemm2
    // NOTE: remap reads csr (separate buffer) + dinv and writes csrp over the dead recs
    // region. recs (30.5 MB) > reg3 slot (51.2 MB) fits; csrp (26.4 MB) fits; h2b (51.2 MB) fits.

    hipMemsetAsync(sums, 0, (size_t)NGRAPH * HDIM * 4, stream);
    hipMemsetAsync(gcnt, 0, (size_t)NBUCK * 4, stream);
    xcast_kernel<<<(NODES * 128 / 4 + 255) / 256, 256, 0, stream>>>(x, xb);
    wcast_kernel<<<(128 * 256 + 256 * 256 + 255) / 256, 256, 0, stream>>>(W1, W2, W1t, W2t);

    fillp1_kernel<<<(ETOT + 16383) / 16384, 1024, 0, stream>>>(erow, ecol, gcnt, recs);
    bscan_kernel <<<1, 256, 0, stream>>>(gcnt, bbase);
    build_kernel <<<NBUCK, 256, 0, stream>>>(recs, gcnt, bbase, rowptr, dinv, csr);
    remap_kernel <<<(ETOT + 255) / 256, 256, 0, stream>>>(csr, dinv, csrp);

    const int AGG_BLOCKS = (NODES / 2 * 64) / 256;    // 2 nodes per wave
    agg1_kernel<<<AGG_BLOCKS, 256, 0, stream>>>(xb, rowptr, csrp, dinv, aggbuf1);

    const int MB = (NODES + 127) / 128;               // 782
    mgemm_kernel<128><<<MB * 2, 256, 0, stream>>>(aggbuf1, W1t, b1, h1b);

    agg2_kernel<<<AGG_BLOCKS, 256, 0, stream>>>(h1b, rowptr, csrp, dinv, aggbuf2);

    mgemm_kernel<256><<<MB * 2, 256, 0, stream>>>(aggbuf2, W2t, b2, h2b);

    pool_kernel<<<dim3((NODES + 1023) / 1024, 4), 256, 0, stream>>>(h2b, bat, sums);

    final_kernel<<<NGRAPH, 64, 0, stream>>>(sums, bat, Wl, bl, out);
}

// Round 7
// 625.989 us; speedup vs baseline: 1.2786x; 1.2786x over previous
//
#include <hip/hip_runtime.h>
#include <hip/hip_bf16.h>
#include <cstddef>

#define NODES  100000
#define EDGES  3200000
#define ETOT   3300000   // EDGES + NODES self-loops
#define NGRAPH 64
#define HDIM   256
#define BSHIFT 9
#define NBUCK  196       // ceil(NODES / 512)
#define BCAP   19456     // records/bucket: mean 16896 + 20 sigma

typedef __hip_bfloat16 bf16;
typedef short bf16x8 __attribute__((ext_vector_type(8)));
typedef float f32x4 __attribute__((ext_vector_type(4)));
typedef float f32x2 __attribute__((ext_vector_type(2)));
typedef unsigned u32x2 __attribute__((ext_vector_type(2)));
typedef unsigned u32x4 __attribute__((ext_vector_type(4)));

__device__ __forceinline__ float blo(unsigned u) { return __uint_as_float(u << 16); }
__device__ __forceinline__ float bhi(unsigned u) { return __uint_as_float(u & 0xffff0000u); }

// ---------------------------------------------------------------- fp32 -> bf16 copy of x
__global__ void xcast_kernel(const float* __restrict__ x, bf16* __restrict__ xb) {
    int i = blockIdx.x * 256 + threadIdx.x;            // 4 elements each
    if ((size_t)i * 4 >= (size_t)NODES * 128) return;
    float4 v = *(const float4*)(x + (size_t)i * 4);
    union { __hip_bfloat162 h[2]; uint2 u; } pk;
    pk.h[0] = __float22bfloat162_rn(make_float2(v.x, v.y));
    pk.h[1] = __float22bfloat162_rn(make_float2(v.z, v.w));
    *(uint2*)(xb + (size_t)i * 4) = pk.u;
}

// ---------------------------------------------------------------- W1/W2 -> transposed bf16
__global__ void wcast_kernel(const float* __restrict__ W1, const float* __restrict__ W2,
                             bf16* __restrict__ W1t, bf16* __restrict__ W2t) {
    int i = blockIdx.x * 256 + threadIdx.x;
    if (i < 128 * 256) {
        int n = i / 128, k = i - n * 128;
        W1t[i] = __float2bfloat16(W1[(size_t)k * 256 + n]);
    } else if (i < 128 * 256 + 256 * 256) {
        int q = i - 128 * 256;
        int n = q / 256, k = q - n * 256;
        W2t[q] = __float2bfloat16(W2[(size_t)k * 256 + n]);
    }
}

// ---------------------------------------------------------------- fill phase 1: bucket records
__global__ __launch_bounds__(1024) void fillp1_kernel(const int* __restrict__ row,
                                                      const int* __restrict__ col,
                                                      int* __restrict__ gcnt,
                                                      uint2* __restrict__ recs) {
    __shared__ int hist[NBUCK];
    __shared__ int base[NBUCK];
    int t = threadIdx.x;
    if (t < NBUCK) hist[t] = 0;
    __syncthreads();
    int e0 = blockIdx.x * 16384;
    int r[16], c[16], rk[16];
    #pragma unroll
    for (int i = 0; i < 16; i++) {
        int e = e0 + i * 1024 + t;
        r[i] = -1;
        if (e < ETOT) {
            if (e < EDGES) { r[i] = row[e]; c[i] = col[e]; }
            else           { r[i] = e - EDGES; c[i] = r[i]; }
            rk[i] = atomicAdd(&hist[c[i] >> BSHIFT], 1);
        }
    }
    __syncthreads();
    if (t < NBUCK && hist[t] > 0) base[t] = atomicAdd(&gcnt[t], hist[t]);
    __syncthreads();
    #pragma unroll
    for (int i = 0; i < 16; i++) {
        if (r[i] >= 0) {
            int b = c[i] >> BSHIFT;
            recs[(size_t)b * BCAP + base[b] + rk[i]] = make_uint2((unsigned)r[i], (unsigned)c[i]);
        }
    }
}

// ---------------------------------------------------------------- bucket base scan (tiny)
__global__ void bscan_kernel(const int* __restrict__ gcnt, int* __restrict__ bbase) {
    __shared__ int part[256];
    int t = threadIdx.x;
    int v0 = (t < NBUCK) ? gcnt[t] : 0;
    part[t] = v0;
    __syncthreads();
    for (int off = 1; off < 256; off <<= 1) {
        int v = (t >= off) ? part[t - off] : 0;
        __syncthreads();
        part[t] += v;
        __syncthreads();
    }
    if (t < NBUCK) bbase[t] = part[t] - v0;   // exclusive
}

// ---------------------------------------------------------------- per-bucket counting sort
__global__ __launch_bounds__(256) void build_kernel(const uint2* __restrict__ recs,
                                                    const int* __restrict__ gcnt,
                                                    const int* __restrict__ bbase,
                                                    int* __restrict__ rowptr,
                                                    float* __restrict__ dinv,
                                                    int* __restrict__ csr) {
    __shared__ int hist[512];
    __shared__ int cur[512];
    __shared__ int part[256];
    const int b = blockIdx.x, t = threadIdx.x;
    const int n0 = b << BSHIFT;
    const int cnt = gcnt[b];
    const int base = bbase[b];
    hist[t] = 0; hist[t + 256] = 0;
    __syncthreads();
    const uint2* rb = recs + (size_t)b * BCAP;
    for (int i = t; i < cnt; i += 256) atomicAdd(&hist[(int)rb[i].y - n0], 1);
    __syncthreads();
    int h0 = hist[2 * t], h1 = hist[2 * t + 1];
    part[t] = h0 + h1;
    __syncthreads();
    for (int off = 1; off < 256; off <<= 1) {
        int v = (t >= off) ? part[t - off] : 0;
        __syncthreads();
        part[t] += v;
        __syncthreads();
    }
    int ex = (t == 0) ? 0 : part[t - 1];       // exclusive over node pairs
    cur[2 * t]     = ex;
    cur[2 * t + 1] = ex + h0;
    int v0 = n0 + 2 * t, v1 = v0 + 1;
    if (v0 < NODES) { rowptr[v0] = base + ex;      dinv[v0] = rsqrtf((float)h0); }
    if (v1 < NODES) { rowptr[v1] = base + ex + h0; dinv[v1] = rsqrtf((float)h1); }
    if (b == 0 && t == 0) rowptr[NODES] = ETOT;
    __syncthreads();
    for (int i = t; i < cnt; i += 256) {
        uint2 r = rb[i];
        int pos = atomicAdd(&cur[(int)r.y - n0], 1);
        csr[base + pos] = (int)r.x;
    }
}

// ---------------------------------------------------------------- pull aggregation, H=128
// 2 nodes per wave: half-wave (32 lanes) per node, uint2 (4 dims) per lane. (R5 form)
__global__ void agg1_kernel(const bf16* __restrict__ xb, const int* __restrict__ rowptr,
                            const int* __restrict__ csr, const float* __restrict__ dinv,
                            bf16* __restrict__ out) {
    int w    = (blockIdx.x * blockDim.x + threadIdx.x) >> 6;
    int lane = threadIdx.x & 63;
    int half = lane >> 5, li = lane & 31;
    int node = w * 2 + half;
    if (node >= NODES) return;
    int beg = rowptr[node], end = rowptr[node + 1];
    float a0 = 0.f, a1 = 0.f, a2 = 0.f, a3 = 0.f;
    int j = beg;
    for (; j + 1 < end; j += 2) {
        int s0 = csr[j], s1 = csr[j + 1];
        float w0 = dinv[s0], w1 = dinv[s1];
        uint2 q0 = *(const uint2*)(xb + (size_t)s0 * 128 + li * 4);
        uint2 q1 = *(const uint2*)(xb + (size_t)s1 * 128 + li * 4);
        a0 += w0 * blo(q0.x) + w1 * blo(q1.x);
        a1 += w0 * bhi(q0.x) + w1 * bhi(q1.x);
        a2 += w0 * blo(q0.y) + w1 * blo(q1.y);
        a3 += w0 * bhi(q0.y) + w1 * bhi(q1.y);
    }
    if (j < end) {
        int s0 = csr[j];
        float w0 = dinv[s0];
        uint2 q0 = *(const uint2*)(xb + (size_t)s0 * 128 + li * 4);
        a0 += w0 * blo(q0.x);
        a1 += w0 * bhi(q0.x);
        a2 += w0 * blo(q0.y);
        a3 += w0 * bhi(q0.y);
    }
    float d = dinv[node];
    union { __hip_bfloat162 h[2]; uint2 u; } pk;
    pk.h[0] = __float22bfloat162_rn(make_float2(a0 * d, a1 * d));
    pk.h[1] = __float22bfloat162_rn(make_float2(a2 * d, a3 * d));
    *(uint2*)(out + (size_t)node * 128 + li * 4) = pk.u;
}

// ---------------------------------------------------------------- pull aggregation, H=256, fp8 src
// 2 nodes/wave, half-wave per node, u32x2 (8 fp8 dims = 8 B) per lane, unroll 4.
__global__ void agg2_kernel(const unsigned char* __restrict__ h8, const int* __restrict__ rowptr,
                            const int* __restrict__ csr, const float* __restrict__ dinv,
                            bf16* __restrict__ out) {
    int w    = (blockIdx.x * blockDim.x + threadIdx.x) >> 6;
    int lane = threadIdx.x & 63;
    int half = lane >> 5, li = lane & 31;
    int node = w * 2 + half;
    if (node >= NODES) return;
    int beg = rowptr[node], end = rowptr[node + 1];
    float a[8] = {};
    int j = beg;
#define ACC8(q, wv) do {                                                   \
        f32x2 d0 = __builtin_amdgcn_cvt_pk_f32_fp8((int)(q).x, false);     \
        f32x2 d1 = __builtin_amdgcn_cvt_pk_f32_fp8((int)(q).x, true);      \
        f32x2 d2 = __builtin_amdgcn_cvt_pk_f32_fp8((int)(q).y, false);     \
        f32x2 d3 = __builtin_amdgcn_cvt_pk_f32_fp8((int)(q).y, true);      \
        a[0] += (wv) * d0.x; a[1] += (wv) * d0.y;                          \
        a[2] += (wv) * d1.x; a[3] += (wv) * d1.y;                          \
        a[4] += (wv) * d2.x; a[5] += (wv) * d2.y;                          \
        a[6] += (wv) * d3.x; a[7] += (wv) * d3.y;                          \
    } while (0)
    for (; j + 3 < end; j += 4) {
        int s0 = csr[j], s1 = csr[j + 1], s2 = csr[j + 2], s3 = csr[j + 3];
        float w0 = dinv[s0], w1 = dinv[s1], w2 = dinv[s2], w3 = dinv[s3];
        u32x2 q0 = *(const u32x2*)(h8 + (size_t)s0 * 256 + li * 8);
        u32x2 q1 = *(const u32x2*)(h8 + (size_t)s1 * 256 + li * 8);
        u32x2 q2 = *(const u32x2*)(h8 + (size_t)s2 * 256 + li * 8);
        u32x2 q3 = *(const u32x2*)(h8 + (size_t)s3 * 256 + li * 8);
        ACC8(q0, w0); ACC8(q1, w1); ACC8(q2, w2); ACC8(q3, w3);
    }
    for (; j < end; j++) {
        int s0 = csr[j];
        float w0 = dinv[s0];
        u32x2 q0 = *(const u32x2*)(h8 + (size_t)s0 * 256 + li * 8);
        ACC8(q0, w0);
    }
#undef ACC8
    float d = dinv[node];
    union { __hip_bfloat162 h[4]; u32x4 u; } pk;
    pk.h[0] = __float22bfloat162_rn(make_float2(a[0] * d, a[1] * d));
    pk.h[1] = __float22bfloat162_rn(make_float2(a[2] * d, a[3] * d));
    pk.h[2] = __float22bfloat162_rn(make_float2(a[4] * d, a[5] * d));
    pk.h[3] = __float22bfloat162_rn(make_float2(a[6] * d, a[7] * d));
    *(u32x4*)(out + (size_t)node * 256 + li * 8) = pk.u;
}

// ---------------------------------------------------------------- bf16 MFMA GEMM 128x128
// C[M,256] = relu(A[M,K] @ B[K,256] + bias). OUT_FP8: write fp8 e4m3, else bf16.
template <int K, bool OUT_FP8>
__global__ __launch_bounds__(256) void mgemm_kernel(const bf16* __restrict__ A,
                                                    const bf16* __restrict__ Bt,
                                                    const float* __restrict__ bias,
                                                    bf16* __restrict__ Cb,
                                                    unsigned char* __restrict__ C8) {
    __shared__ short As[128][40];   // [m][k], +8 pad
    __shared__ short Bs[128][40];   // [n][k]
    const int t    = threadIdx.x;
    const int bm   = (int)(blockIdx.x >> 1) * 128;
    const int bn   = (int)(blockIdx.x & 1) * 128;
    const int lane = t & 63;
    const int wave = t >> 6;
    const int wm   = (wave >> 1) * 64, wn = (wave & 1) * 64;
    const int m16  = lane & 15, kq = lane >> 4;
    f32x4 acc[4][4] = {};

    for (int k0 = 0; k0 < K; k0 += 32) {
        #pragma unroll
        for (int h = 0; h < 2; h++) {
            int q = t * 2 + h;
            int rr = q >> 2, seg = q & 3;
            uint4 va = {0u, 0u, 0u, 0u};
            int grow = bm + rr;
            if (grow < NODES) va = *(const uint4*)(A + (size_t)grow * K + k0 + seg * 8);
            *(uint4*)&As[rr][seg * 8] = va;
            uint4 vb = *(const uint4*)(Bt + (size_t)(bn + rr) * K + k0 + seg * 8);
            *(uint4*)&Bs[rr][seg * 8] = vb;
        }
        __syncthreads();
        bf16x8 af[4], bf_[4];
        #pragma unroll
        for (int i = 0; i < 4; i++) {
            af[i]  = *(const bf16x8*)&As[wm + i * 16 + m16][kq * 8];
            bf_[i] = *(const bf16x8*)&Bs[wn + i * 16 + m16][kq * 8];
        }
        #pragma unroll
        for (int mt = 0; mt < 4; mt++)
            #pragma unroll
            for (int nt = 0; nt < 4; nt++)
                acc[mt][nt] = __builtin_amdgcn_mfma_f32_16x16x32_bf16(af[mt], bf_[nt],
                                                                     acc[mt][nt], 0, 0, 0);
        __syncthreads();
    }

    // C/D layout: col = lane&15, row = (lane>>4)*4 + reg
    #pragma unroll
    for (int mt = 0; mt < 4; mt++) {
        #pragma unroll
        for (int r = 0; r < 4; r++) {
            int row = bm + wm + mt * 16 + kq * 4 + r;
            if (row >= NODES) continue;
            #pragma unroll
            for (int nt = 0; nt < 4; nt++) {
                int colb = bn + wn + nt * 16 + m16;
                float v = fmaxf(acc[mt][nt][r] + bias[colb], 0.f);
                if (OUT_FP8) {
                    int pkd = __builtin_amdgcn_cvt_pk_fp8_f32(v, v, 0, false);
                    C8[(size_t)row * 256 + colb] = (unsigned char)(pkd & 0xff);
                } else {
                    Cb[(size_t)row * 256 + colb] = __float2bfloat16(v);
                }
            }
        }
    }
}

// ---------------------------------------------------------------- segmented mean-pool sum
__global__ void pool_kernel(const bf16* __restrict__ h2, const int* __restrict__ batch,
                            float* __restrict__ sums) {
    int lane = threadIdx.x & 63;
    int sub  = threadIdx.x >> 6;                   // 0..3
    int col  = blockIdx.y * 64 + lane;
    int r0   = blockIdx.x * 1024 + sub * 256;
    if (r0 >= NODES) return;
    int r1 = r0 + 256; if (r1 > NODES) r1 = NODES;
    float acc = 0.f;
    int g = batch[r0];
    for (int r = r0; r < r1; r++) {
        int gg = batch[r];
        if (gg != g) { atomicAdd(&sums[g * 256 + col], acc); acc = 0.f; g = gg; }
        acc += __bfloat162float(h2[(size_t)r * 256 + col]);
    }
    atomicAdd(&sums[g * 256 + col], acc);
}

// ---------------------------------------------------------------- pooled @ Wl + bl
__global__ void final_kernel(const float* __restrict__ sums, const int* __restrict__ batch,
                             const float* __restrict__ Wl, const float* __restrict__ bl,
                             float* __restrict__ out) {
    int g = blockIdx.x;
    int l = threadIdx.x;
    int lo = 0, hi = NODES;
    while (lo < hi) { int m = (lo + hi) >> 1; if (batch[m] < g) lo = m + 1; else hi = m; }
    int lb = lo;
    lo = lb; hi = NODES;
    while (lo < hi) { int m = (lo + hi) >> 1; if (batch[m] <= g) lo = m + 1; else hi = m; }
    int cnt = lo - lb;
    float inv = 1.f / fmaxf((float)cnt, 1.f);
    float a0 = 0.f, a1 = 0.f;
    for (int k = l; k < 256; k += 64) {
        float p = sums[g * 256 + k] * inv;
        a0 += p * Wl[k * 2 + 0];
        a1 += p * Wl[k * 2 + 1];
    }
    for (int off = 32; off > 0; off >>= 1) {
        a0 += __shfl_down(a0, off, 64);
        a1 += __shfl_down(a1, off, 64);
    }
    if (l == 0) {
        out[g * 2 + 0] = a0 + bl[0];
        out[g * 2 + 1] = a1 + bl[1];
    }
}

// ---------------------------------------------------------------- launch
extern "C" void kernel_launch(void* const* d_in, const int* in_sizes, int n_in,
                              void* d_out, int out_size, void* d_ws, size_t ws_size,
                              hipStream_t stream) {
    const float* x    = (const float*)d_in[0];
    const int*   ei   = (const int*)d_in[1];
    const int*   bat  = (const int*)d_in[2];
    const float* W1   = (const float*)d_in[3];
    const float* b1   = (const float*)d_in[4];
    const float* W2   = (const float*)d_in[5];
    const float* b2   = (const float*)d_in[6];
    const float* Wl   = (const float*)d_in[7];
    const float* bl   = (const float*)d_in[8];
    float*       out  = (float*)d_out;
    const int* erow = ei;           // edge_index[0] = source
    const int* ecol = ei + EDGES;   // edge_index[1] = target

    char* p = (char*)d_ws;
    auto take = [&](size_t bytes) {
        char* r = p;
        p += (bytes + 255) & ~(size_t)255;
        return r;
    };
    float* dinv   = (float*)take((size_t)NODES * 4);
    int*   rowptr = (int*)  take((size_t)(NODES + 1) * 4);
    int*   gcnt   = (int*)  take((size_t)NBUCK * 4);
    int*   bbase  = (int*)  take((size_t)NBUCK * 4);
    int*   csr    = (int*)  take((size_t)ETOT * 4);
    float* sums   = (float*)take((size_t)NGRAPH * HDIM * 4);
    bf16*  W1t    = (bf16*) take((size_t)128 * 256 * 2);
    bf16*  W2t    = (bf16*) take((size_t)256 * 256 * 2);
    char*  reg1   = (char*) take((size_t)NODES * HDIM * 2);          // xb -> h1f8
    char*  reg2   = (char*) take((size_t)NODES * HDIM * 2);          // aggbuf1 -> aggbuf2
    char*  reg3   = (char*) take((size_t)NODES * HDIM * 2);          // recs -> h2b
    bf16*          xb      = (bf16*)reg1;          // 25.6 MB, dead after agg1
    unsigned char* h1f8    = (unsigned char*)reg1; // 25.6 MB, born mgemm1, dead after agg2
    bf16*          aggbuf1 = (bf16*)reg2;          // born agg1, dead after mgemm1
    bf16*          aggbuf2 = (bf16*)reg2;          // born agg2, dead after mgemm2
    uint2*         recs    = (uint2*)reg3;         // 30.5 MB, dead after build
    bf16*          h2b     = (bf16*)reg3;          // 51.2 MB, born mgemm2

    hipMemsetAsync(sums, 0, (size_t)NGRAPH * HDIM * 4, stream);
    hipMemsetAsync(gcnt, 0, (size_t)NBUCK * 4, stream);
    xcast_kernel<<<(NODES * 128 / 4 + 255) / 256, 256, 0, stream>>>(x, xb);
    wcast_kernel<<<(128 * 256 + 256 * 256 + 255) / 256, 256, 0, stream>>>(W1, W2, W1t, W2t);

    fillp1_kernel<<<(ETOT + 16383) / 16384, 1024, 0, stream>>>(erow, ecol, gcnt, recs);
    bscan_kernel <<<1, 256, 0, stream>>>(gcnt, bbase);
    build_kernel <<<NBUCK, 256, 0, stream>>>(recs, gcnt, bbase, rowptr, dinv, csr);

    const int AGG_BLOCKS = (NODES / 2 * 64) / 256;    // 2 nodes per wave
    agg1_kernel<<<AGG_BLOCKS, 256, 0, stream>>>(xb, rowptr, csr, dinv, aggbuf1);

    const int MB = (NODES + 127) / 128;               // 782
    mgemm_kernel<128, true ><<<MB * 2, 256, 0, stream>>>(aggbuf1, W1t, b1, nullptr, h1f8);

    agg2_kernel<<<AGG_BLOCKS, 256, 0, stream>>>(h1f8, rowptr, csr, dinv, aggbuf2);

    mgemm_kernel<256, false><<<MB * 2, 256, 0, stream>>>(aggbuf2, W2t, b2, h2b, nullptr);

    pool_kernel<<<dim3((NODES + 1023) / 1024, 4), 256, 0, stream>>>(h2b, bat, sums);

    final_kernel<<<NGRAPH, 64, 0, stream>>>(sums, bat, Wl, bl, out);
}

// Round 8
// 560.772 us; speedup vs baseline: 1.4273x; 1.1163x over previous
//
#include <hip/hip_runtime.h>
#include <hip/hip_bf16.h>
#include <cstddef>

#define NODES  100000
#define EDGES  3200000
#define ETOT   3300000   // EDGES + NODES self-loops
#define NGRAPH 64
#define HDIM   256
#define BSHIFT 9
#define NBUCK  196       // ceil(NODES / 512)
#define BCAP   19456     // records/bucket: mean 16896 + 20 sigma

typedef __hip_bfloat16 bf16;
typedef short bf16x8 __attribute__((ext_vector_type(8)));
typedef float f32x4 __attribute__((ext_vector_type(4)));
typedef float f32x2 __attribute__((ext_vector_type(2)));
typedef unsigned u32x2 __attribute__((ext_vector_type(2)));
typedef unsigned u32x4 __attribute__((ext_vector_type(4)));

// ---------------------------------------------------------------- fp32 -> fp8 copy of x
__global__ void xcast_kernel(const float* __restrict__ x, unsigned char* __restrict__ x8) {
    int i = blockIdx.x * 256 + threadIdx.x;            // 4 elements each
    if ((size_t)i * 4 >= (size_t)NODES * 128) return;
    float4 v = *(const float4*)(x + (size_t)i * 4);
    int w = __builtin_amdgcn_cvt_pk_fp8_f32(v.x, v.y, 0, false);
    w     = __builtin_amdgcn_cvt_pk_fp8_f32(v.z, v.w, w, true);
    *(unsigned*)(x8 + (size_t)i * 4) = (unsigned)w;
}

// ---------------------------------------------------------------- W1/W2 -> transposed bf16
__global__ void wcast_kernel(const float* __restrict__ W1, const float* __restrict__ W2,
                             bf16* __restrict__ W1t, bf16* __restrict__ W2t) {
    int i = blockIdx.x * 256 + threadIdx.x;
    if (i < 128 * 256) {
        int n = i / 128, k = i - n * 128;
        W1t[i] = __float2bfloat16(W1[(size_t)k * 256 + n]);
    } else if (i < 128 * 256 + 256 * 256) {
        int q = i - 128 * 256;
        int n = q / 256, k = q - n * 256;
        W2t[q] = __float2bfloat16(W2[(size_t)k * 256 + n]);
    }
}

// ---------------------------------------------------------------- fill phase 1: bucket records
// 4-copy LDS histogram (hist[t&3][b]) quarters rank-atomic collisions.
__global__ __launch_bounds__(1024) void fillp1_kernel(const int* __restrict__ row,
                                                      const int* __restrict__ col,
                                                      int* __restrict__ gcnt,
                                                      uint2* __restrict__ recs) {
    __shared__ int hist[4][NBUCK];
    __shared__ int coff[4][NBUCK];
    __shared__ int base[NBUCK];
    int t  = threadIdx.x;
    int cp = t & 3;
    for (int i = t; i < 4 * NBUCK; i += 1024) ((int*)hist)[i] = 0;
    __syncthreads();
    int e0 = blockIdx.x * 16384;
    int r[16], c[16], rk[16];
    #pragma unroll
    for (int i = 0; i < 16; i++) {
        int e = e0 + i * 1024 + t;
        r[i] = -1;
        if (e < ETOT) {
            if (e < EDGES) { r[i] = row[e]; c[i] = col[e]; }
            else           { r[i] = e - EDGES; c[i] = r[i]; }
            rk[i] = atomicAdd(&hist[cp][c[i] >> BSHIFT], 1);
        }
    }
    __syncthreads();
    if (t < NBUCK) {
        int h0 = hist[0][t], h1 = hist[1][t], h2 = hist[2][t], h3 = hist[3][t];
        coff[0][t] = 0; coff[1][t] = h0; coff[2][t] = h0 + h1; coff[3][t] = h0 + h1 + h2;
        int tot = h0 + h1 + h2 + h3;
        base[t] = (tot > 0) ? atomicAdd(&gcnt[t], tot) : 0;
    }
    __syncthreads();
    #pragma unroll
    for (int i = 0; i < 16; i++) {
        if (r[i] >= 0) {
            int b = c[i] >> BSHIFT;
            recs[(size_t)b * BCAP + base[b] + coff[cp][b] + rk[i]] =
                make_uint2((unsigned)r[i], (unsigned)c[i]);
        }
    }
}

// ---------------------------------------------------------------- bucket base scan (tiny)
__global__ void bscan_kernel(const int* __restrict__ gcnt, int* __restrict__ bbase) {
    __shared__ int part[256];
    int t = threadIdx.x;
    int v0 = (t < NBUCK) ? gcnt[t] : 0;
    part[t] = v0;
    __syncthreads();
    for (int off = 1; off < 256; off <<= 1) {
        int v = (t >= off) ? part[t - off] : 0;
        __syncthreads();
        part[t] += v;
        __syncthreads();
    }
    if (t < NBUCK) bbase[t] = part[t] - v0;   // exclusive
}

// ---------------------------------------------------------------- per-bucket counting sort
__global__ __launch_bounds__(256) void build_kernel(const uint2* __restrict__ recs,
                                                    const int* __restrict__ gcnt,
                                                    const int* __restrict__ bbase,
                                                    int* __restrict__ rowptr,
                                                    float* __restrict__ dinv,
                                                    int* __restrict__ csr) {
    __shared__ int hist[512];
    __shared__ int cur[512];
    __shared__ int part[256];
    const int b = blockIdx.x, t = threadIdx.x;
    const int n0 = b << BSHIFT;
    const int cnt = gcnt[b];
    const int base = bbase[b];
    hist[t] = 0; hist[t + 256] = 0;
    __syncthreads();
    const uint2* rb = recs + (size_t)b * BCAP;
    for (int i = t; i < cnt; i += 256) atomicAdd(&hist[(int)rb[i].y - n0], 1);
    __syncthreads();
    int h0 = hist[2 * t], h1 = hist[2 * t + 1];
    part[t] = h0 + h1;
    __syncthreads();
    for (int off = 1; off < 256; off <<= 1) {
        int v = (t >= off) ? part[t - off] : 0;
        __syncthreads();
        part[t] += v;
        __syncthreads();
    }
    int ex = (t == 0) ? 0 : part[t - 1];       // exclusive over node pairs
    cur[2 * t]     = ex;
    cur[2 * t + 1] = ex + h0;
    int v0 = n0 + 2 * t, v1 = v0 + 1;
    if (v0 < NODES) { rowptr[v0] = base + ex;      dinv[v0] = rsqrtf((float)h0); }
    if (v1 < NODES) { rowptr[v1] = base + ex + h0; dinv[v1] = rsqrtf((float)h1); }
    if (b == 0 && t == 0) rowptr[NODES] = ETOT;
    __syncthreads();
    for (int i = t; i < cnt; i += 256) {
        uint2 r = rb[i];
        int pos = atomicAdd(&cur[(int)r.y - n0], 1);
        csr[base + pos] = (int)r.x;
    }
}

// ---------------------------------------------------------------- pull aggregation, H=128, fp8 src
// 2 nodes/wave, half-wave per node, u32 (4 fp8 dims) per lane, unroll 4.
__global__ void agg1_kernel(const unsigned char* __restrict__ x8, const int* __restrict__ rowptr,
                            const int* __restrict__ csr, const float* __restrict__ dinv,
                            bf16* __restrict__ out) {
    int w    = (blockIdx.x * blockDim.x + threadIdx.x) >> 6;
    int lane = threadIdx.x & 63;
    int half = lane >> 5, li = lane & 31;
    int node = w * 2 + half;
    if (node >= NODES) return;
    int beg = rowptr[node], end = rowptr[node + 1];
    float a0 = 0.f, a1 = 0.f, a2 = 0.f, a3 = 0.f;
    int j = beg;
#define ACC4(q, wv) do {                                                   \
        f32x2 d0 = __builtin_amdgcn_cvt_pk_f32_fp8((int)(q), false);       \
        f32x2 d1 = __builtin_amdgcn_cvt_pk_f32_fp8((int)(q), true);        \
        a0 += (wv) * d0.x; a1 += (wv) * d0.y;                              \
        a2 += (wv) * d1.x; a3 += (wv) * d1.y;                              \
    } while (0)
    for (; j + 3 < end; j += 4) {
        int s0 = csr[j], s1 = csr[j + 1], s2 = csr[j + 2], s3 = csr[j + 3];
        float w0 = dinv[s0], w1 = dinv[s1], w2 = dinv[s2], w3 = dinv[s3];
        unsigned q0 = *(const unsigned*)(x8 + (size_t)s0 * 128 + li * 4);
        unsigned q1 = *(const unsigned*)(x8 + (size_t)s1 * 128 + li * 4);
        unsigned q2 = *(const unsigned*)(x8 + (size_t)s2 * 128 + li * 4);
        unsigned q3 = *(const unsigned*)(x8 + (size_t)s3 * 128 + li * 4);
        ACC4(q0, w0); ACC4(q1, w1); ACC4(q2, w2); ACC4(q3, w3);
    }
    for (; j < end; j++) {
        int s0 = csr[j];
        float w0 = dinv[s0];
        unsigned q0 = *(const unsigned*)(x8 + (size_t)s0 * 128 + li * 4);
        ACC4(q0, w0);
    }
#undef ACC4
    float d = dinv[node];
    union { __hip_bfloat162 h[2]; u32x2 u; } pk;
    pk.h[0] = __float22bfloat162_rn(make_float2(a0 * d, a1 * d));
    pk.h[1] = __float22bfloat162_rn(make_float2(a2 * d, a3 * d));
    *(u32x2*)(out + (size_t)node * 128 + li * 4) = pk.u;
}

// ---------------------------------------------------------------- pull aggregation, H=256, fp8 src
// 2 nodes/wave, half-wave per node, u32x2 (8 fp8 dims) per lane, unroll 4.
__global__ void agg2_kernel(const unsigned char* __restrict__ h8, const int* __restrict__ rowptr,
                            const int* __restrict__ csr, const float* __restrict__ dinv,
                            bf16* __restrict__ out) {
    int w    = (blockIdx.x * blockDim.x + threadIdx.x) >> 6;
    int lane = threadIdx.x & 63;
    int half = lane >> 5, li = lane & 31;
    int node = w * 2 + half;
    if (node >= NODES) return;
    int beg = rowptr[node], end = rowptr[node + 1];
    float a[8] = {};
    int j = beg;
#define ACC8(q, wv) do {                                                   \
        f32x2 d0 = __builtin_amdgcn_cvt_pk_f32_fp8((int)(q).x, false);     \
        f32x2 d1 = __builtin_amdgcn_cvt_pk_f32_fp8((int)(q).x, true);      \
        f32x2 d2 = __builtin_amdgcn_cvt_pk_f32_fp8((int)(q).y, false);     \
        f32x2 d3 = __builtin_amdgcn_cvt_pk_f32_fp8((int)(q).y, true);      \
        a[0] += (wv) * d0.x; a[1] += (wv) * d0.y;                          \
        a[2] += (wv) * d1.x; a[3] += (wv) * d1.y;                          \
        a[4] += (wv) * d2.x; a[5] += (wv) * d2.y;                          \
        a[6] += (wv) * d3.x; a[7] += (wv) * d3.y;                          \
    } while (0)
    for (; j + 3 < end; j += 4) {
        int s0 = csr[j], s1 = csr[j + 1], s2 = csr[j + 2], s3 = csr[j + 3];
        float w0 = dinv[s0], w1 = dinv[s1], w2 = dinv[s2], w3 = dinv[s3];
        u32x2 q0 = *(const u32x2*)(h8 + (size_t)s0 * 256 + li * 8);
        u32x2 q1 = *(const u32x2*)(h8 + (size_t)s1 * 256 + li * 8);
        u32x2 q2 = *(const u32x2*)(h8 + (size_t)s2 * 256 + li * 8);
        u32x2 q3 = *(const u32x2*)(h8 + (size_t)s3 * 256 + li * 8);
        ACC8(q0, w0); ACC8(q1, w1); ACC8(q2, w2); ACC8(q3, w3);
    }
    for (; j < end; j++) {
        int s0 = csr[j];
        float w0 = dinv[s0];
        u32x2 q0 = *(const u32x2*)(h8 + (size_t)s0 * 256 + li * 8);
        ACC8(q0, w0);
    }
#undef ACC8
    float d = dinv[node];
    union { __hip_bfloat162 h[4]; u32x4 u; } pk;
    pk.h[0] = __float22bfloat162_rn(make_float2(a[0] * d, a[1] * d));
    pk.h[1] = __float22bfloat162_rn(make_float2(a[2] * d, a[3] * d));
    pk.h[2] = __float22bfloat162_rn(make_float2(a[4] * d, a[5] * d));
    pk.h[3] = __float22bfloat162_rn(make_float2(a[6] * d, a[7] * d));
    *(u32x4*)(out + (size_t)node * 256 + li * 8) = pk.u;
}

// ---------------------------------------------------------------- bf16 MFMA GEMM 128x128, fp8 out
// C[M,256] = relu(A[M,K] @ B[K,256] + bias), written as fp8 e4m3.
template <int K>
__global__ __launch_bounds__(256) void mgemm_kernel(const bf16* __restrict__ A,
                                                    const bf16* __restrict__ Bt,
                                                    const float* __restrict__ bias,
                                                    unsigned char* __restrict__ C8) {
    __shared__ short As[128][40];   // [m][k], +8 pad
    __shared__ short Bs[128][40];   // [n][k]
    const int t    = threadIdx.x;
    const int bm   = (int)(blockIdx.x >> 1) * 128;
    const int bn   = (int)(blockIdx.x & 1) * 128;
    const int lane = t & 63;
    const int wave = t >> 6;
    const int wm   = (wave >> 1) * 64, wn = (wave & 1) * 64;
    const int m16  = lane & 15, kq = lane >> 4;
    f32x4 acc[4][4] = {};

    for (int k0 = 0; k0 < K; k0 += 32) {
        #pragma unroll
        for (int h = 0; h < 2; h++) {
            int q = t * 2 + h;
            int rr = q >> 2, seg = q & 3;
            uint4 va = {0u, 0u, 0u, 0u};
            int grow = bm + rr;
            if (grow < NODES) va = *(const uint4*)(A + (size_t)grow * K + k0 + seg * 8);
            *(uint4*)&As[rr][seg * 8] = va;
            uint4 vb = *(const uint4*)(Bt + (size_t)(bn + rr) * K + k0 + seg * 8);
            *(uint4*)&Bs[rr][seg * 8] = vb;
        }
        __syncthreads();
        bf16x8 af[4], bf_[4];
        #pragma unroll
        for (int i = 0; i < 4; i++) {
            af[i]  = *(const bf16x8*)&As[wm + i * 16 + m16][kq * 8];
            bf_[i] = *(const bf16x8*)&Bs[wn + i * 16 + m16][kq * 8];
        }
        #pragma unroll
        for (int mt = 0; mt < 4; mt++)
            #pragma unroll
            for (int nt = 0; nt < 4; nt++)
                acc[mt][nt] = __builtin_amdgcn_mfma_f32_16x16x32_bf16(af[mt], bf_[nt],
                                                                     acc[mt][nt], 0, 0, 0);
        __syncthreads();
    }

    // C/D layout: col = lane&15, row = (lane>>4)*4 + reg
    #pragma unroll
    for (int mt = 0; mt < 4; mt++) {
        #pragma unroll
        for (int r = 0; r < 4; r++) {
            int row = bm + wm + mt * 16 + kq * 4 + r;
            if (row >= NODES) continue;
            #pragma unroll
            for (int nt = 0; nt < 4; nt++) {
                int colb = bn + wn + nt * 16 + m16;
                float v = fmaxf(acc[mt][nt][r] + bias[colb], 0.f);
                int pkd = __builtin_amdgcn_cvt_pk_fp8_f32(v, v, 0, false);
                C8[(size_t)row * 256 + colb] = (unsigned char)(pkd & 0xff);
            }
        }
    }
}

// ---------------------------------------------------------------- segmented mean-pool sum (fp8 in)
// 64 lanes x 4 cols = 256 cols per sub-wave; batch SORTED, one flush per boundary.
__global__ void pool_kernel(const unsigned char* __restrict__ h2, const int* __restrict__ batch,
                            float* __restrict__ sums) {
    int lane = threadIdx.x & 63;                   // 4 cols each
    int sub  = threadIdx.x >> 6;                   // 0..3
    int r0   = blockIdx.x * 1024 + sub * 256;
    if (r0 >= NODES) return;
    int r1 = r0 + 256; if (r1 > NODES) r1 = NODES;
    float a0 = 0.f, a1 = 0.f, a2 = 0.f, a3 = 0.f;
    int g = batch[r0];
    int cb = lane * 4;
    for (int r = r0; r < r1; r++) {
        int gg = batch[r];
        if (gg != g) {
            atomicAdd(&sums[g * 256 + cb + 0], a0);
            atomicAdd(&sums[g * 256 + cb + 1], a1);
            atomicAdd(&sums[g * 256 + cb + 2], a2);
            atomicAdd(&sums[g * 256 + cb + 3], a3);
            a0 = a1 = a2 = a3 = 0.f; g = gg;
        }
        unsigned q = *(const unsigned*)(h2 + (size_t)r * 256 + cb);
        f32x2 d0 = __builtin_amdgcn_cvt_pk_f32_fp8((int)q, false);
        f32x2 d1 = __builtin_amdgcn_cvt_pk_f32_fp8((int)q, true);
        a0 += d0.x; a1 += d0.y; a2 += d1.x; a3 += d1.y;
    }
    atomicAdd(&sums[g * 256 + cb + 0], a0);
    atomicAdd(&sums[g * 256 + cb + 1], a1);
    atomicAdd(&sums[g * 256 + cb + 2], a2);
    atomicAdd(&sums[g * 256 + cb + 3], a3);
}

// ---------------------------------------------------------------- pooled @ Wl + bl
__global__ void final_kernel(const float* __restrict__ sums, const int* __restrict__ batch,
                             const float* __restrict__ Wl, const float* __restrict__ bl,
                             float* __restrict__ out) {
    int g = blockIdx.x;
    int l = threadIdx.x;
    int lo = 0, hi = NODES;
    while (lo < hi) { int m = (lo + hi) >> 1; if (batch[m] < g) lo = m + 1; else hi = m; }
    int lb = lo;
    lo = lb; hi = NODES;
    while (lo < hi) { int m = (lo + hi) >> 1; if (batch[m] <= g) lo = m + 1; else hi = m; }
    int cnt = lo - lb;
    float inv = 1.f / fmaxf((float)cnt, 1.f);
    float a0 = 0.f, a1 = 0.f;
    for (int k = l; k < 256; k += 64) {
        float p = sums[g * 256 + k] * inv;
        a0 += p * Wl[k * 2 + 0];
        a1 += p * Wl[k * 2 + 1];
    }
    for (int off = 32; off > 0; off >>= 1) {
        a0 += __shfl_down(a0, off, 64);
        a1 += __shfl_down(a1, off, 64);
    }
    if (l == 0) {
        out[g * 2 + 0] = a0 + bl[0];
        out[g * 2 + 1] = a1 + bl[1];
    }
}

// ---------------------------------------------------------------- launch
extern "C" void kernel_launch(void* const* d_in, const int* in_sizes, int n_in,
                              void* d_out, int out_size, void* d_ws, size_t ws_size,
                              hipStream_t stream) {
    const float* x    = (const float*)d_in[0];
    const int*   ei   = (const int*)d_in[1];
    const int*   bat  = (const int*)d_in[2];
    const float* W1   = (const float*)d_in[3];
    const float* b1   = (const float*)d_in[4];
    const float* W2   = (const float*)d_in[5];
    const float* b2   = (const float*)d_in[6];
    const float* Wl   = (const float*)d_in[7];
    const float* bl   = (const float*)d_in[8];
    float*       out  = (float*)d_out;
    const int* erow = ei;           // edge_index[0] = source
    const int* ecol = ei + EDGES;   // edge_index[1] = target

    char* p = (char*)d_ws;
    auto take = [&](size_t bytes) {
        char* r = p;
        p += (bytes + 255) & ~(size_t)255;
        return r;
    };
    float* dinv   = (float*)take((size_t)NODES * 4);
    int*   rowptr = (int*)  take((size_t)(NODES + 1) * 4);
    int*   gcnt   = (int*)  take((size_t)NBUCK * 4);
    int*   bbase  = (int*)  take((size_t)NBUCK * 4);
    int*   csr    = (int*)  take((size_t)ETOT * 4);
    float* sums   = (float*)take((size_t)NGRAPH * HDIM * 4);
    bf16*  W1t    = (bf16*) take((size_t)128 * 256 * 2);
    bf16*  W2t    = (bf16*) take((size_t)256 * 256 * 2);
    char*  reg1   = (char*) take((size_t)NODES * HDIM * 1);          // x8 -> h1f8
    char*  reg2   = (char*) take((size_t)NODES * HDIM * 2);          // aggbuf1 -> aggbuf2
    char*  reg3   = (char*) take((size_t)NBUCK * BCAP * 8);          // recs -> h2f8
    unsigned char* x8      = (unsigned char*)reg1; // 12.8 MB, dead after agg1
    unsigned char* h1f8    = (unsigned char*)reg1; // 25.6 MB, born mgemm1, dead after agg2
    bf16*          aggbuf1 = (bf16*)reg2;          // 25.6 MB, born agg1, dead after mgemm1
    bf16*          aggbuf2 = (bf16*)reg2;          // 51.2 MB, born agg2, dead after mgemm2
    uint2*         recs    = (uint2*)reg3;         // 30.5 MB, dead after build
    unsigned char* h2f8    = (unsigned char*)reg3; // 25.6 MB, born mgemm2
    // NOTE: reg1 sized NODES*HDIM*1 = 25.6 MB (h1f8 H=256 x 1 B); x8 (12.8 MB) fits.

    hipMemsetAsync(sums, 0, (size_t)NGRAPH * HDIM * 4, stream);
    hipMemsetAsync(gcnt, 0, (size_t)NBUCK * 4, stream);
    xcast_kernel<<<(NODES * 128 / 4 + 255) / 256, 256, 0, stream>>>(x, x8);
    wcast_kernel<<<(128 * 256 + 256 * 256 + 255) / 256, 256, 0, stream>>>(W1, W2, W1t, W2t);

    fillp1_kernel<<<(ETOT + 16383) / 16384, 1024, 0, stream>>>(erow, ecol, gcnt, recs);
    bscan_kernel <<<1, 256, 0, stream>>>(gcnt, bbase);
    build_kernel <<<NBUCK, 256, 0, stream>>>(recs, gcnt, bbase, rowptr, dinv, csr);

    const int AGG_BLOCKS = (NODES / 2 * 64) / 256;    // 2 nodes per wave
    agg1_kernel<<<AGG_BLOCKS, 256, 0, stream>>>(x8, rowptr, csr, dinv, aggbuf1);

    const int MB = (NODES + 127) / 128;               // 782
    mgemm_kernel<128><<<MB * 2, 256, 0, stream>>>(aggbuf1, W1t, b1, h1f8);

    agg2_kernel<<<AGG_BLOCKS, 256, 0, stream>>>(h1f8, rowptr, csr, dinv, aggbuf2);

    mgemm_kernel<256><<<MB * 2, 256, 0, stream>>>(aggbuf2, W2t, b2, h2f8);

    pool_kernel<<<(NODES + 1023) / 1024, 256, 0, stream>>>(h2f8, bat, sums);

    final_kernel<<<NGRAPH, 64, 0, stream>>>(sums, bat, Wl, bl, out);
}